// Round 3
// baseline (6963.488 us; speedup 1.0000x reference)
//
#include <hip/hip_runtime.h>
#include <hip/hip_bf16.h>
#include <math.h>

// ---------------------------------------------------------------------------
// DecoderTARDIS forward, fp32, persistent-kernel version.
//   prologue: pack Wcat/Wicat, addrW(+T), init (incl. barrier ctr), icat GEMM
//   persist_kernel <<<256,512>>>: 32 steps, 3 phases/step, custom grid barrier
//     A: hcat = h@Wcat           (168 blocks, 16x64 tiles, LDS)
//     L: logits tanh + gumbel + per-half argmax (256 blocks = 2/batch)
//     S: softmax-denom/r/gates/LSTM/val/valW/u2w (128 blocks = 1/batch)
// Sparse-memory model: valHist/valWHist + lastWriter instead of dense mem.
// ---------------------------------------------------------------------------

static constexpr int LL    = 32;
static constexpr int BB    = 128;
static constexpr int ID    = 512;
static constexpr int HD    = 1024;
static constexpr int NS    = 512;
static constexpr int AA    = 128;
static constexpr int CCd   = 128;
static constexpr int AC    = 256;
static constexpr int WC    = 1344;
static constexpr int COL_W0  = 1024;
static constexpr int COL_G0  = 1280;
static constexpr int COL_AB0 = 1283;
static constexpr int COL_TAU = 1285;
static constexpr int GRID_P  = 256;

// ------------------------------ threefry -----------------------------------
__device__ __forceinline__ uint32_t rotl32(uint32_t x, uint32_t r) {
  return (x << r) | (x >> (32u - r));
}

__device__ __forceinline__ void threefry2x32(uint32_t k0, uint32_t k1,
                                             uint32_t x0, uint32_t x1,
                                             uint32_t& o0, uint32_t& o1) {
  uint32_t ks0 = k0, ks1 = k1, ks2 = 0x1BD11BDAu ^ k0 ^ k1;
  x0 += ks0; x1 += ks1;
#define TFR(r) { x0 += x1; x1 = rotl32(x1, r); x1 ^= x0; }
  TFR(13u) TFR(15u) TFR(26u) TFR(6u)   x0 += ks1; x1 += ks2 + 1u;
  TFR(17u) TFR(29u) TFR(16u) TFR(24u)  x0 += ks2; x1 += ks0 + 2u;
  TFR(13u) TFR(15u) TFR(26u) TFR(6u)   x0 += ks0; x1 += ks1 + 3u;
  TFR(17u) TFR(29u) TFR(16u) TFR(24u)  x0 += ks1; x1 += ks2 + 4u;
  TFR(13u) TFR(15u) TFR(26u) TFR(6u)   x0 += ks2; x1 += ks0 + 5u;
#undef TFR
  o0 = x0; o1 = x1;
}

__device__ __forceinline__ float bits_to_gumbel(uint32_t bits) {
  uint32_t v = (bits >> 9) | 0x3F800000u;
  float f = __uint_as_float(v) - 1.0f;
  if (f <= 0.0f) f = 1.17549435e-38f;
  return -logf(-logf(f));
}

// ------------------------------ grid barrier -------------------------------
__device__ __forceinline__ void grid_barrier(unsigned int* ctr, unsigned int& target) {
  __syncthreads();
  if (threadIdx.x == 0) {
    target += GRID_P;
    __hip_atomic_fetch_add(ctr, 1u, __ATOMIC_RELEASE, __HIP_MEMORY_SCOPE_AGENT);
    while (__hip_atomic_load(ctr, __ATOMIC_RELAXED, __HIP_MEMORY_SCOPE_AGENT) < target) {
      __builtin_amdgcn_s_sleep(1);
    }
    (void)__hip_atomic_load(ctr, __ATOMIC_ACQUIRE, __HIP_MEMORY_SCOPE_AGENT);
  }
  __syncthreads();
}

// ------------------------------ prologue -----------------------------------
__global__ void pack_wcat(const float* __restrict__ Wh2c, const float* __restrict__ Wh2w,
                          const float* __restrict__ Wh2g, const float* __restrict__ Wh2ab,
                          const float* __restrict__ Wh2tau, float* __restrict__ Wcat) {
  int idx = blockIdx.x * blockDim.x + threadIdx.x;
  if (idx >= HD * WC) return;
  int k = idx / WC, c = idx % WC;
  float v = 0.0f;
  if (c < 1024)       v = Wh2c[(size_t)k * HD + c];
  else if (c < 1280)  v = Wh2w[(size_t)k * AC + (c - 1024)];
  else if (c < 1283)  v = Wh2g[k * 3 + (c - 1280)];
  else if (c < 1285)  v = Wh2ab[k * 2 + (c - 1283)];
  else if (c == 1285) v = Wh2tau[k];
  Wcat[idx] = v;
}

__global__ void pack_wicat(const float* __restrict__ Wi2c, const float* __restrict__ Wi2w,
                           const float* __restrict__ Wi2g, const float* __restrict__ Wi2ab,
                           float* __restrict__ Wicat) {
  int idx = blockIdx.x * blockDim.x + threadIdx.x;
  if (idx >= ID * WC) return;
  int k = idx / WC, c = idx % WC;
  float v = 0.0f;
  if (c < 1024)      v = Wi2c[(size_t)k * HD + c];
  else if (c < 1280) v = Wi2w[(size_t)k * AC + (c - 1024)];
  else if (c < 1283) v = Wi2g[k * 3 + (c - 1280)];
  else if (c < 1285) v = Wi2ab[k * 2 + (c - 1283)];
  Wicat[idx] = v;
}

__global__ void addrw_kernel(const float* __restrict__ mem_bias,
                             const float* __restrict__ Wm2w,
                             float* __restrict__ addrW, float* __restrict__ addrWT) {
  int idx = blockIdx.x * blockDim.x + threadIdx.x;
  if (idx >= NS * AC) return;
  int n = idx / AC, m = idx % AC;
  float acc = 0.0f;
  for (int k = 0; k < AA; k++) acc += mem_bias[(size_t)n * AC + k] * Wm2w[(size_t)k * AC + m];
  addrW[(size_t)n * AC + m] = acc;
  addrWT[(size_t)m * NS + n] = acc;
}

__global__ void init_kernel(const float* __restrict__ hid, float* __restrict__ h,
                            float* __restrict__ cc, float* __restrict__ w_sum,
                            int* __restrict__ lastWriter, float* __restrict__ u2w,
                            unsigned int* __restrict__ bar_ctr) {
  int idx = blockIdx.x * blockDim.x + threadIdx.x;
  if (idx < BB * HD) { h[idx] = hid[idx]; cc[idx] = 0.0f; }
  if (idx < BB * NS) { w_sum[idx] = 0.0f; lastWriter[idx] = -1; }
  if (idx < BB * AC) { u2w[idx] = 0.0f; }
  if (idx == 0) bar_ctr[0] = 0u;
}

// ---------------- big fp32 GEMM (icat = inp @ Wicat), 64x64 tile -----------
__global__ __launch_bounds__(256) void gemm_big(const float* __restrict__ A,
                                                const float* __restrict__ W,
                                                float* __restrict__ C,
                                                int M, int K, int Nw) {
  __shared__ float sAT[32][68];
  __shared__ float sW[32][68];
  int tx = threadIdx.x & 15, ty = threadIdx.x >> 4;
  int m0 = blockIdx.x * 64, n0 = blockIdx.y * 64;
  float acc[4][4] = {};
  for (int k0 = 0; k0 < K; k0 += 32) {
    for (int i = threadIdx.x; i < 64 * 32; i += 256) {
      int r = i >> 5, kk = i & 31;
      sAT[kk][r] = A[(size_t)(m0 + r) * K + k0 + kk];
    }
    for (int i = threadIdx.x; i < 32 * 64; i += 256) {
      int kk = i >> 6, c = i & 63;
      sW[kk][c] = W[(size_t)(k0 + kk) * Nw + n0 + c];
    }
    __syncthreads();
#pragma unroll
    for (int kk = 0; kk < 32; kk++) {
      float4 a = *(const float4*)&sAT[kk][ty * 4];
      float4 b = *(const float4*)&sW[kk][tx * 4];
      acc[0][0] += a.x * b.x; acc[0][1] += a.x * b.y; acc[0][2] += a.x * b.z; acc[0][3] += a.x * b.w;
      acc[1][0] += a.y * b.x; acc[1][1] += a.y * b.y; acc[1][2] += a.y * b.z; acc[1][3] += a.y * b.w;
      acc[2][0] += a.z * b.x; acc[2][1] += a.z * b.y; acc[2][2] += a.z * b.z; acc[2][3] += a.z * b.w;
      acc[3][0] += a.w * b.x; acc[3][1] += a.w * b.y; acc[3][2] += a.w * b.z; acc[3][3] += a.w * b.w;
    }
    __syncthreads();
  }
#pragma unroll
  for (int i = 0; i < 4; i++) {
    float4 st = make_float4(acc[i][0], acc[i][1], acc[i][2], acc[i][3]);
    *(float4*)&C[(size_t)(m0 + ty * 4 + i) * Nw + n0 + tx * 4] = st;
  }
}

// ------------------------------ persistent kernel --------------------------
struct SMemA { float sA[64][18]; float sW[64][68]; };
struct SMemL { float bias[AC]; float att[AC]; float zl[256]; float avv[256]; int aii[256]; };
struct SMemS { float rs[AC]; float hs[HD]; float vhalf[512]; float vs[CCd]; float zn[512]; };
union SMemU { SMemA a; SMemL l; SMemS s; };

__global__ __launch_bounds__(512) void persist_kernel(
    const float* __restrict__ icat, const float* __restrict__ Wcat,
    const float* __restrict__ addrW, const float* __restrict__ addrWT,
    const float* __restrict__ atten, const float* __restrict__ mem_bias,
    const float* __restrict__ Wr2g, const float* __restrict__ Wr2ab,
    const float* __restrict__ Wr2c, const float* __restrict__ Wh2m,
    const float* __restrict__ Wm2w, const float* __restrict__ Wu2w,
    const float* __restrict__ b_h2tau,
    float* hbuf, float* ccbuf, float* w_sum, float* u2w,
    float* valHist, float* valWHist, int* lastWriter, int* writePos,
    float* hcat, float* zbuf, float* gmaxv, int* gmaxi,
    unsigned int* bar_ctr, float* out) {
  const int blk = blockIdx.x, tid = threadIdx.x;
  const int lane = tid & 63, wv = tid >> 6;
  __shared__ SMemU sm;
  __shared__ float red[8], gdot[5], s_fio[3], s_ab[2], s_tau, s_zmax;
  __shared__ int s_ns;
  unsigned int target = 0;

  uint32_t k1a, k1b, k2a, k2b;
  threefry2x32(0u, 42u, 0u, 0u, k1a, k1b);
  threefry2x32(0u, 42u, 0u, 1u, k2a, k2b);

  for (int t = 0; t < LL; ++t) {
    // ---------------- phase A: hcat = h @ Wcat (168 blocks) ----------------
    if (blk < 168) {
      const int m0 = (blk & 7) * 16, n0 = (blk >> 3) * 64;
      const int col = tid & 63, rg2 = (tid >> 6) * 2;
      float acc0 = 0.0f, acc1 = 0.0f;
      for (int k0 = 0; k0 < HD; k0 += 64) {
        __syncthreads();
        for (int i = tid; i < 16 * 64; i += 512) {
          int r = i >> 6, kk = i & 63;
          sm.a.sA[kk][r] = hbuf[(size_t)(m0 + r) * HD + k0 + kk];
        }
        for (int i = tid; i < 64 * 64; i += 512) {
          int kk = i >> 6, c = i & 63;
          sm.a.sW[kk][c] = Wcat[(size_t)(k0 + kk) * WC + n0 + c];
        }
        __syncthreads();
#pragma unroll 8
        for (int kk = 0; kk < 64; ++kk) {
          float2 a2 = *(const float2*)&sm.a.sA[kk][rg2];
          float w = sm.a.sW[kk][col];
          acc0 += a2.x * w; acc1 += a2.y * w;
        }
      }
      hcat[(size_t)(m0 + rg2) * WC + n0 + col] = acc0;
      hcat[(size_t)(m0 + rg2 + 1) * WC + n0 + col] = acc1;
    }
    grid_barrier(bar_ctr, target);

    // ---------------- phase L: logits + gumbel + half-argmax (256 blocks) --
    {
      const int b = blk >> 1, half = blk & 1, nbase = half * 256;
      if (tid < AC) {
        sm.l.bias[tid] = hcat[(size_t)b * WC + COL_W0 + tid] +
                         icat[(size_t)(t * BB + b) * WC + COL_W0 + tid] +
                         u2w[(size_t)b * AC + tid];
        sm.l.att[tid] = atten[tid];
      }
      __syncthreads();
      {
        const int nn = tid >> 1, kh = (tid & 1) * 128;
        const int n = nbase + nn;
        float p = 0.0f;
        const float* awt = addrWT + n;
#pragma unroll 4
        for (int k = kh; k < kh + 128; ++k)
          p += tanhf(sm.l.bias[k] + awt[(size_t)k * NS]) * sm.l.att[k];
        p += __shfl_xor(p, 1, 64);
        if ((tid & 1) == 0) sm.l.zl[nn] = p;
      }
      __syncthreads();
      for (int j = wv; j < t; j += 8) {
        int n2 = writePos[b * LL + j];
        if (n2 >= nbase && n2 < nbase + 256) {
          int s = lastWriter[b * NS + n2];
          const float* dw = valWHist + ((size_t)b * LL + s) * AC;
          const float* aw = addrW + (size_t)n2 * AC;
          float q = 0.0f;
          for (int k = lane; k < AC; k += 64)
            q += tanhf(sm.l.bias[k] + aw[k] + dw[k]) * sm.l.att[k];
          for (int off = 32; off; off >>= 1) q += __shfl_down(q, off, 64);
          if (lane == 0) sm.l.zl[n2 - nbase] = q;
        }
      }
      __syncthreads();
      if (tid < 256) {
        uint32_t gi = (uint32_t)((t * BB + b) * NS + nbase + tid);
        uint32_t o0, o1; threefry2x32(k1a, k1b, 0u, gi, o0, o1);
        float zb = sm.l.zl[tid] + bits_to_gumbel(o0 ^ o1);
        zbuf[(size_t)b * NS + nbase + tid] = zb;
        sm.l.avv[tid] = zb; sm.l.aii[tid] = nbase + tid;
      }
      __syncthreads();
      for (int off = 128; off; off >>= 1) {
        if (tid < off) {
          float c2 = sm.l.avv[tid + off]; int i2 = sm.l.aii[tid + off];
          if (c2 > sm.l.avv[tid] || (c2 == sm.l.avv[tid] && i2 < sm.l.aii[tid])) {
            sm.l.avv[tid] = c2; sm.l.aii[tid] = i2;
          }
        }
        __syncthreads();
      }
      if (tid == 0) { gmaxv[b * 2 + half] = sm.l.avv[0]; gmaxi[b * 2 + half] = sm.l.aii[0]; }
    }
    grid_barrier(bar_ctr, target);

    // ---------------- phase S: select/update/val/u2w (128 blocks) ----------
    if (blk < BB) {
      const int b = blk;
      const float* icrow = icat + (size_t)(t * BB + b) * WC;
      if (tid == 0) {
        float v0 = gmaxv[2 * b], v1 = gmaxv[2 * b + 1];
        int   i0 = gmaxi[2 * b], i1 = gmaxi[2 * b + 1];
        if (v1 > v0 || (v1 == v0 && i1 < i0)) { s_zmax = v1; s_ns = i1; }
        else { s_zmax = v0; s_ns = i0; }
        float x = hcat[(size_t)b * WC + COL_TAU] + b_h2tau[0];
        s_tau = fmaxf(x, 0.0f) + log1pf(expf(-fabsf(x))) + 1.0f;
      }
      __syncthreads();
      const float tau = s_tau, zmax = s_zmax; const int ns = s_ns;
      {
        float e = expf((zbuf[(size_t)b * NS + tid] - zmax) / tau);
        for (int off = 32; off; off >>= 1) e += __shfl_down(e, off, 64);
        if (lane == 0) red[wv] = e;
      }
      __syncthreads();
      const float D = red[0] + red[1] + red[2] + red[3] + red[4] + red[5] + red[6] + red[7];
      const float ystar = 1.0f / D;
      const float ws = (1.0f - ystar) + ystar;
      if (tid < AC) {
        int sW_ = lastWriter[b * NS + ns];
        float mv = (tid < AA) ? mem_bias[(size_t)ns * AC + tid]
                 : ((sW_ >= 0) ? valHist[((size_t)b * LL + sW_) * CCd + (tid - AA)] : 0.0f);
        sm.s.rs[tid] = ws * mv;
      }
      __syncthreads();
      if (tid == 0) {  // bookkeeping AFTER r-gather read lastWriter
        int pos = (t * LL < NS) ? (t * LL) : ns;
        writePos[b * LL + t] = pos;
        lastWriter[b * NS + pos] = t;
        w_sum[(size_t)b * NS + ns] += ws;
      }
      if (tid < 160) {
        int j = tid >> 5, l = tid & 31;
        float p = 0.0f;
        if (j < 3) { for (int k = l; k < AC; k += 32) p += sm.s.rs[k] * Wr2g[k * 3 + j]; }
        else { int jj = j - 3; for (int k = l; k < AC; k += 32) p += sm.s.rs[k] * Wr2ab[k * 2 + jj]; }
        for (int off = 16; off; off >>= 1) p += __shfl_down(p, off, 32);
        if (l == 0) gdot[j] = p;
      }
      __syncthreads();
      if (tid < 3) {
        float x = hcat[(size_t)b * WC + COL_G0 + tid] + icrow[COL_G0 + tid] + gdot[tid];
        s_fio[tid] = 1.0f / (1.0f + expf(-x));
      } else if (tid < 5) {
        int j = tid - 3;
        float x = hcat[(size_t)b * WC + COL_AB0 + j] + icrow[COL_AB0 + j] + gdot[tid];
        uint32_t i1 = (uint32_t)(((t * BB + b) * 2 + j) * 2);
        uint32_t o0, o1;
        threefry2x32(k2a, k2b, 0u, i1, o0, o1);     float g1 = bits_to_gumbel(o0 ^ o1);
        threefry2x32(k2a, k2b, 0u, i1 + 1, o0, o1); float g2 = bits_to_gumbel(o0 ^ o1);
        s_ab[j] = (x + g1 - g2) > 0.0f ? 1.0f : 0.0f;
      }
      __syncthreads();
      const float fg = s_fio[0], ig = s_fio[1], og = s_fio[2];
      const float alpha = s_ab[0], beta = s_ab[1];
      const int c0 = tid * 2;
      {
        float r0 = 0.0f, r1 = 0.0f;
#pragma unroll 4
        for (int k = 0; k < AC; ++k) {
          float rk = sm.s.rs[k];
          float2 w2 = *(const float2*)&Wr2c[(size_t)k * HD + c0];
          r0 += rk * w2.x; r1 += rk * w2.y;
        }
        float2 hc2 = *(const float2*)&hcat[(size_t)b * WC + c0];
        float2 ic2 = *(const float2*)&icrow[c0];
        float2 cc2 = *(const float2*)&ccbuf[(size_t)b * HD + c0];
        float a0 = beta * hc2.x + ic2.x + alpha * r0;
        float a1 = beta * hc2.y + ic2.y + alpha * r1;
        float cn0 = fg * cc2.x + ig * tanhf(a0);
        float cn1 = fg * cc2.y + ig * tanhf(a1);
        float hn0 = og * tanhf(cn0), hn1 = og * tanhf(cn1);
        *(float2*)&ccbuf[(size_t)b * HD + c0] = make_float2(cn0, cn1);
        *(float2*)&hbuf[(size_t)b * HD + c0] = make_float2(hn0, hn1);
        *(float2*)&out[((size_t)t * BB + b) * HD + c0] = make_float2(hn0, hn1);
        sm.s.hs[c0] = hn0; sm.s.hs[c0 + 1] = hn1;
      }
      __syncthreads();
      {  // val = h @ Wh2m (4-way split-K)
        int c = tid & 127, q = tid >> 7;
        const float* wp = Wh2m + c;
        float acc = 0.0f;
        int kb = q * 256;
#pragma unroll 4
        for (int k = kb; k < kb + 256; ++k) acc += sm.s.hs[k] * wp[(size_t)k * CCd];
        sm.s.vhalf[tid] = acc;
      }
      __syncthreads();
      if (tid < CCd) {
        float val = sm.s.vhalf[tid] + sm.s.vhalf[tid + 128] + sm.s.vhalf[tid + 256] + sm.s.vhalf[tid + 384];
        sm.s.vs[tid] = val;
        valHist[((size_t)b * LL + t) * CCd + tid] = val;
      }
      __syncthreads();
      {  // valW = val @ Wm2w[A:,:] (2-way split)
        int m = tid & 255, h2 = tid >> 8;
        float acc = 0.0f;
        int cb = h2 * 64;
#pragma unroll 4
        for (int c = cb; c < cb + 64; ++c) acc += sm.s.vs[c] * Wm2w[(size_t)(AA + c) * AC + m];
        sm.s.zn[tid] = acc;
      }
      __syncthreads();
      if (tid < AC) valWHist[((size_t)b * LL + t) * AC + tid] = sm.s.zn[tid] + sm.s.zn[tid + 256];
      __syncthreads();
      if (t + 1 < LL) {  // u2w for next step (w_sum already committed above)
        float v = w_sum[(size_t)b * NS + tid];
        float ssum = v;
        for (int off = 32; off; off >>= 1) ssum += __shfl_down(ssum, off, 64);
        if (lane == 0) red[wv] = ssum;
        __syncthreads();
        float mu = (red[0] + red[1] + red[2] + red[3] + red[4] + red[5] + red[6] + red[7]) / (float)NS;
        __syncthreads();
        float d = (v - mu) * (v - mu);
        for (int off = 32; off; off >>= 1) d += __shfl_down(d, off, 64);
        if (lane == 0) red[wv] = d;
        __syncthreads();
        float var = (red[0] + red[1] + red[2] + red[3] + red[4] + red[5] + red[6] + red[7]) / (float)NS;
        float rsq = rsqrtf(var + 1e-5f);
        sm.s.zn[tid] = (v - mu) * rsq;
        __syncthreads();
        {
          int m = tid & 255, h2 = tid >> 8;
          float acc = 0.0f;
          int kb2 = h2 * 256;
#pragma unroll 4
          for (int k = kb2; k < kb2 + 256; ++k) acc += sm.s.zn[k] * Wu2w[(size_t)k * AC + m];
          sm.s.vhalf[tid] = acc;
        }
        __syncthreads();
        if (tid < AC) u2w[(size_t)b * AC + tid] = sm.s.vhalf[tid] + sm.s.vhalf[tid + 256];
      }
    }
    grid_barrier(bar_ctr, target);
  }
}

// ------------------------------ host ---------------------------------------
extern "C" void kernel_launch(void* const* d_in, const int* in_sizes, int n_in,
                              void* d_out, int out_size, void* d_ws, size_t ws_size,
                              hipStream_t stream) {
  const float* inp      = (const float*)d_in[0];
  const float* hid      = (const float*)d_in[1];
  const float* mem_bias = (const float*)d_in[2];
  const float* W_h2w    = (const float*)d_in[3];
  const float* W_i2w    = (const float*)d_in[4];
  const float* W_m2w    = (const float*)d_in[5];
  const float* W_u2w    = (const float*)d_in[6];
  const float* W_h2g    = (const float*)d_in[7];
  const float* W_i2g    = (const float*)d_in[8];
  const float* W_r2g    = (const float*)d_in[9];
  const float* W_h2ab   = (const float*)d_in[10];
  const float* W_i2ab   = (const float*)d_in[11];
  const float* W_r2ab   = (const float*)d_in[12];
  const float* W_h2c    = (const float*)d_in[13];
  const float* W_i2c    = (const float*)d_in[14];
  const float* W_r2c    = (const float*)d_in[15];
  const float* atten    = (const float*)d_in[16];
  const float* W_h2tau  = (const float*)d_in[17];
  const float* b_h2tau  = (const float*)d_in[18];
  const float* W_h2m    = (const float*)d_in[19];
  float* out = (float*)d_out;

  char* base = (char*)d_ws;
  size_t off = 0;
  auto alloc = [&](size_t elems) -> void* {
    void* p = (void*)(base + off);
    off += ((elems * 4 + 255) / 256) * 256;
    return p;
  };
  float* icat     = (float*)alloc((size_t)LL * BB * WC);
  float* Wicat    = (float*)alloc((size_t)ID * WC);
  float* Wcat     = (float*)alloc((size_t)HD * WC);
  float* addrW    = (float*)alloc((size_t)NS * AC);
  float* addrWT   = (float*)alloc((size_t)NS * AC);
  float* hbuf     = (float*)alloc((size_t)BB * HD);
  float* ccbuf    = (float*)alloc((size_t)BB * HD);
  float* w_sum    = (float*)alloc((size_t)BB * NS);
  float* u2w      = (float*)alloc((size_t)BB * AC);
  float* valHist  = (float*)alloc((size_t)BB * LL * CCd);
  float* valWHist = (float*)alloc((size_t)BB * LL * AC);
  float* hcat     = (float*)alloc((size_t)BB * WC);
  float* zbuf     = (float*)alloc((size_t)BB * NS);
  float* gmaxv    = (float*)alloc((size_t)BB * 2);
  int*   gmaxi    = (int*)alloc((size_t)BB * 2);
  int*   writePos = (int*)alloc((size_t)BB * LL);
  int*   lastWriter = (int*)alloc((size_t)BB * NS);
  unsigned int* bar_ctr = (unsigned int*)alloc(64);

  hipLaunchKernelGGL(pack_wcat, dim3((HD * WC + 255) / 256), dim3(256), 0, stream,
                     W_h2c, W_h2w, W_h2g, W_h2ab, W_h2tau, Wcat);
  hipLaunchKernelGGL(pack_wicat, dim3((ID * WC + 255) / 256), dim3(256), 0, stream,
                     W_i2c, W_i2w, W_i2g, W_i2ab, Wicat);
  hipLaunchKernelGGL(addrw_kernel, dim3((NS * AC + 255) / 256), dim3(256), 0, stream,
                     mem_bias, W_m2w, addrW, addrWT);
  hipLaunchKernelGGL(init_kernel, dim3((BB * HD + 255) / 256), dim3(256), 0, stream,
                     hid, hbuf, ccbuf, w_sum, lastWriter, u2w, bar_ctr);
  hipLaunchKernelGGL(gemm_big, dim3((LL * BB) / 64, WC / 64), dim3(256), 0, stream,
                     inp, Wicat, icat, LL * BB, ID, WC);
  hipLaunchKernelGGL(persist_kernel, dim3(GRID_P), dim3(512), 0, stream,
                     icat, Wcat, addrW, addrWT, atten, mem_bias,
                     W_r2g, W_r2ab, W_r2c, W_h2m, W_m2w, W_u2w, b_h2tau,
                     hbuf, ccbuf, w_sum, u2w, valHist, valWHist,
                     lastWriter, writePos, hcat, zbuf, gmaxv, gmaxi,
                     bar_ctr, out);
}